// Round 1
// baseline (183.406 us; speedup 1.0000x reference)
//
#include <hip/hip_runtime.h>
#include <math.h>

// ---------------------------------------------------------------------------
// TropicalMLP: h = logsumexp_j(x_j + w_ij) + b_i  ==  log(sum_j e^x_j e^w_ij) + b_i
// => each layer is an fp32 GEMM on pre-exponentiated operands + log epilogue.
// Safe without max-subtraction: all intermediate values bounded (|z| < ~6).
// ---------------------------------------------------------------------------

__global__ __launch_bounds__(256) void exp_kernel(const float* __restrict__ in,
                                                  float* __restrict__ out, int n4) {
    int i = blockIdx.x * 256 + threadIdx.x;
    if (i >= n4) return;
    float4 v = reinterpret_cast<const float4*>(in)[i];
    float4 r;
    r.x = expf(v.x); r.y = expf(v.y); r.z = expf(v.z); r.w = expf(v.w);
    reinterpret_cast<float4*>(out)[i] = r;
}

// out[m,n] = logf(sum_k A[m,k] * Bw[n,k]) + bias[n]
// A: M x K row-major, Bw: N x K row-major ("NT" gemm, both K-contiguous).
// BM=64, BN=32, BK=16, 256 threads, 4x2 micro-tile.
__global__ __launch_bounds__(256) void gemm_log_bias(
    const float* __restrict__ A, const float* __restrict__ Bw,
    const float* __restrict__ bias, float* __restrict__ out,
    int M, int N, int K)
{
    __shared__ float As[16][64];
    __shared__ float Bs[16][32];
    const int tid = threadIdx.x;
    const int bx = blockIdx.x, by = blockIdx.y;
    const int tx = tid & 15, ty = tid >> 4;

    const float* Ab = A + (by * 64) * K;
    const float* Bb = Bw + (bx * 32) * K;

    const int ar = tid >> 2, ak = (tid & 3) << 2;  // A tile: 64 rows x 16 k
    const int br = tid >> 3, bk = (tid & 7) << 1;  // B tile: 32 rows x 16 k

    float acc[4][2] = {};

    for (int k0 = 0; k0 < K; k0 += 16) {
        float4 av = *reinterpret_cast<const float4*>(Ab + ar * K + k0 + ak);
        float2 bv = *reinterpret_cast<const float2*>(Bb + br * K + k0 + bk);
        __syncthreads();
        As[ak + 0][ar] = av.x;
        As[ak + 1][ar] = av.y;
        As[ak + 2][ar] = av.z;
        As[ak + 3][ar] = av.w;
        Bs[bk + 0][br] = bv.x;
        Bs[bk + 1][br] = bv.y;
        __syncthreads();
#pragma unroll
        for (int kk = 0; kk < 16; ++kk) {
            float4 a = *reinterpret_cast<const float4*>(&As[kk][ty * 4]);
            float2 b = *reinterpret_cast<const float2*>(&Bs[kk][tx * 2]);
            acc[0][0] += a.x * b.x; acc[0][1] += a.x * b.y;
            acc[1][0] += a.y * b.x; acc[1][1] += a.y * b.y;
            acc[2][0] += a.z * b.x; acc[2][1] += a.z * b.y;
            acc[3][0] += a.w * b.x; acc[3][1] += a.w * b.y;
        }
    }
    const int row0 = by * 64 + ty * 4;
    const int col0 = bx * 32 + tx * 2;
    float bi0 = bias[col0], bi1 = bias[col0 + 1];
#pragma unroll
    for (int i = 0; i < 4; ++i) {
        float2 o;
        o.x = logf(acc[i][0]) + bi0;
        o.y = logf(acc[i][1]) + bi1;
        *reinterpret_cast<float2*>(out + (row0 + i) * N + col0) = o;
    }
}

// Tropical layernorm + relu + exp (prep for next layer's GEMM).
// One block per row of 512. Exact order stats via bitonic sort in LDS.
// med = s[255] (lower-middle), q25 = s[127]+0.75*(s[128]-s[127]),
// q75 = s[383]+0.25*(s[384]-s[383])  (numpy 'linear' quantile, n=512).
__global__ __launch_bounds__(256) void ln_relu_exp_kernel(
    const float* __restrict__ H, const float* __restrict__ lw,
    const float* __restrict__ lb, float* __restrict__ Aout)
{
    __shared__ float s[512];
    const int b = blockIdx.x;
    const int tid = threadIdx.x;
    const float* row = H + b * 512;
    s[tid] = row[tid];
    s[tid + 256] = row[tid + 256];

    for (int k = 2; k <= 512; k <<= 1) {
        for (int j = k >> 1; j > 0; j >>= 1) {
            __syncthreads();
            int idx = ((tid & ~(j - 1)) << 1) | (tid & (j - 1));
            int p = idx | j;
            float a = s[idx], c = s[p];
            bool asc = (idx & k) == 0;
            if (asc ? (a > c) : (a < c)) { s[idx] = c; s[p] = a; }
        }
    }
    __syncthreads();
    float med = s[255];
    float q25 = s[127] + 0.75f * (s[128] - s[127]);
    float q75 = s[383] + 0.25f * (s[384] - s[383]);
    float iqr = fmaxf(q75 - q25, 1e-6f);
    float inv = 1.0f / iqr;
#pragma unroll
    for (int t = 0; t < 2; ++t) {
        int j = tid + t * 256;
        float v = (row[j] - med) * inv * lw[j] + lb[j];
        v = fmaxf(v, 0.0f);
        Aout[b * 512 + j] = expf(v);
    }
}

extern "C" void kernel_launch(void* const* d_in, const int* in_sizes, int n_in,
                              void* d_out, int out_size, void* d_ws, size_t ws_size,
                              hipStream_t stream) {
    const float* x    = (const float*)d_in[0];
    const float* w1   = (const float*)d_in[1];
    const float* b1   = (const float*)d_in[2];
    const float* ln1w = (const float*)d_in[3];
    const float* ln1b = (const float*)d_in[4];
    const float* w2   = (const float*)d_in[5];
    const float* b2   = (const float*)d_in[6];
    const float* ln2w = (const float*)d_in[7];
    const float* ln2b = (const float*)d_in[8];
    const float* w3   = (const float*)d_in[9];
    const float* b3   = (const float*)d_in[10];
    float* out = (float*)d_out;

    const int B = 1024, DIN = 512, DH = 512, DOUT = 256;

    float* ws   = (float*)d_ws;
    float* Abuf = ws;                 // B*DH   = 524288 floats (exp'd activations)
    float* Hbuf = Abuf + B * DH;      // B*DH   = 524288 floats (pre-LN layer out)
    float* Ew   = Hbuf + B * DH;      // DH*DIN = 262144 floats (exp'd weights, reused)
    // total: 5.25 MB

    // exp(x) -> Abuf
    exp_kernel<<<(B * DIN / 4 + 255) / 256, 256, 0, stream>>>(x, Abuf, B * DIN / 4);

    // layer 1
    exp_kernel<<<(DH * DIN / 4 + 255) / 256, 256, 0, stream>>>(w1, Ew, DH * DIN / 4);
    gemm_log_bias<<<dim3(DH / 32, B / 64), 256, 0, stream>>>(Abuf, Ew, b1, Hbuf, B, DH, DIN);
    ln_relu_exp_kernel<<<B, 256, 0, stream>>>(Hbuf, ln1w, ln1b, Abuf);

    // layer 2
    exp_kernel<<<(DH * DH / 4 + 255) / 256, 256, 0, stream>>>(w2, Ew, DH * DH / 4);
    gemm_log_bias<<<dim3(DH / 32, B / 64), 256, 0, stream>>>(Abuf, Ew, b2, Hbuf, B, DH, DH);
    ln_relu_exp_kernel<<<B, 256, 0, stream>>>(Hbuf, ln2w, ln2b, Abuf);

    // layer 3 (no LN/relu after; log+bias straight to d_out)
    exp_kernel<<<(DOUT * DH / 4 + 255) / 256, 256, 0, stream>>>(w3, Ew, DOUT * DH / 4);
    gemm_log_bias<<<dim3(DOUT / 32, B / 64), 256, 0, stream>>>(Abuf, Ew, b3, out, B, DOUT, DH);
}